// Round 7
// baseline (240.253 us; speedup 1.0000x reference)
//
#include <hip/hip_runtime.h>
#include <stdint.h>

#define IN_DIM 512
#define CB 8192
#define CD 16
#define NROWS 32768
#define DELTA 2e-3f
#define FMAXV 3.402823466e38f

typedef short bf16x8 __attribute__((ext_vector_type(8)));
typedef float f32x4 __attribute__((ext_vector_type(4)));

__device__ inline unsigned short f2bf(float x) {
    unsigned u = __float_as_uint(x);
    unsigned r = u + 0x7FFFu + ((u >> 16) & 1u);   // RNE
    return (unsigned short)(r >> 16);
}
__device__ inline float bf2f(unsigned short h) { return __uint_as_float(((unsigned)h) << 16); }

// ---------------- K0: csq (R1-bit-exact) + B-fragment prep + counter zero ----------------
__global__ __launch_bounds__(256) void prep_kernel(const float* __restrict__ cb,
                                                   float* __restrict__ csq,
                                                   bf16x8* __restrict__ B1,
                                                   bf16x8* __restrict__ B2,
                                                   bf16x8* __restrict__ B3,
                                                   int* __restrict__ counter) {
    int id = blockIdx.x * 256 + threadIdx.x;  // 0..32767
    if (id == 0) counter[0] = 0;
    if (id < CB) {   // SOURCE-IDENTICAL csq expression (bit-exact vs R1)
        const float4* p = (const float4*)(cb + (size_t)id * CD);
        float s = 0.f;
#pragma unroll
        for (int j = 0; j < 4; ++j) {
            float4 v = p[j];
            s += v.x * v.x + v.y * v.y + v.z * v.z + v.w * v.w;
        }
        csq[id] = s;
    }
    // 3-term bf16 split fragments: B1=[c1|c1], B2=[c2|c2], B3=[c3|c1] (pairs A2=[t1|t3])
    int slot = id & 63;
    int nt = id >> 6;
    int q = slot >> 4;
    int n = nt * 16 + (slot & 15);
    int d0 = (q & 1) * 8;
    bool lo = (q < 2);
    const float* src = cb + (size_t)n * CD + d0;
    bf16x8 v1, v2, v3;
#pragma unroll
    for (int j = 0; j < 8; ++j) {
        float x = src[j];
        unsigned short a = f2bf(x);
        float r = x - bf2f(a);
        unsigned short b = f2bf(r);
        float r2 = r - bf2f(b);
        unsigned short c = f2bf(r2);
        v1[j] = (short)a;
        v2[j] = (short)b;
        v3[j] = (short)(lo ? c : a);
    }
    B1[id] = v1;
    B2[id] = v2;
    B3[id] = v3;
}

// ---------------- K1: projection — R1's EXACT arithmetic DAG, thread=(row,d) ----------------
// Per (row,d): 4 chunk partials, each sum_{j=0..31} (v.x*w0+v.y*w1+v.z*w2+v.w*w3)
// over dims c*128+j*4.., combined ((c0+c1)+c2)+c3, *(-2)  — identical expression
// tree to R1 (bits preserved; only the lane assignment changed).
// Block 256 = 16 d x 16 rows; input loads broadcast across the 16 d-lanes.
__global__ __launch_bounds__(256) void proj_kernel(const float* __restrict__ in,
                                                   const float* __restrict__ W,
                                                   float* __restrict__ tprime) {
    __shared__ float WL[16 * 516];   // stride 516: banks 2-way only (free)
#pragma unroll
    for (int i = 0; i < 32; ++i) {
        int idx = threadIdx.x + i * 256;       // 0..8191
        WL[(idx >> 9) * 516 + (idx & 511)] = W[idx];
    }
    __syncthreads();

    int tid = threadIdx.x;
    int d = tid & 15;
    int rloc = tid >> 4;
    int row = blockIdx.x * 16 + rloc;
    const float4* ip = (const float4*)(in + (size_t)row * IN_DIM);

    float acc[4];
#pragma unroll
    for (int c = 0; c < 4; ++c) acc[c] = 0.f;

#pragma unroll 4
    for (int j = 0; j < 32; ++j) {
#pragma unroll
        for (int c = 0; c < 4; ++c) {
            float4 v = ip[c * 32 + j];
            const float* w = WL + d * 516 + c * 128 + j * 4;
            acc[c] += v.x * w[0] + v.y * w[1] + v.z * w[2] + v.w * w[3];
        }
    }
    float t = -2.f * (((acc[0] + acc[1]) + acc[2]) + acc[3]);
    tprime[(size_t)row * CD + d] = t;
}

// ---------------- K2: 3-MFMA scan, 4 rowgroups/wave (64 rows), eighth/wave ----------------
// Block 512 = 8 waves; block covers 64 rows; wave w scans eighth w (64 tiles).
// Each B-tile read feeds 12 MFMAs (4 rowgroups) -> 4x less L2 traffic than R6.
__global__ __launch_bounds__(512, 4) void scan_kernel(
        const float* __restrict__ tprime, const float* __restrict__ csq,
        const bf16x8* __restrict__ B1, const bf16x8* __restrict__ B2,
        const bf16x8* __restrict__ B3,
        int* __restrict__ out, int* __restrict__ queue, int* __restrict__ counter) {
    __shared__ float tbuf[64][17];
    __shared__ float m_s1[64][8];
    __shared__ float m_s2[64][8];
    __shared__ int   m_i1[64][8];

    int tid = threadIdx.x;
    int lane = tid & 63;
    int w = __builtin_amdgcn_readfirstlane(tid >> 6);
    int rowbase = blockIdx.x * 64;

    {
        int i0 = tid, i1 = tid + 512;
        tbuf[i0 >> 4][i0 & 15] = tprime[(size_t)rowbase * CD + i0];
        tbuf[i1 >> 4][i1 & 15] = tprime[(size_t)rowbase * CD + i1];
    }
    __syncthreads();

    int q = lane >> 4;
    int col = lane & 15;
    int d0 = (q & 1) * 8;
    bool lo = (q < 2);

    bf16x8 A1[4], A2[4];   // per rowgroup g: A1=[t1|t2], A2=[t1|t3]
#pragma unroll
    for (int g = 0; g < 4; ++g) {
        int arow = 16 * g + col;
#pragma unroll
        for (int j = 0; j < 8; ++j) {
            float x = tbuf[arow][d0 + j];
            unsigned short t1 = f2bf(x);
            float r = x - bf2f(t1);
            unsigned short t2 = f2bf(r);
            float r2 = r - bf2f(t2);
            unsigned short t3 = f2bf(r2);
            A1[g][j] = (short)(lo ? t1 : t2);
            A2[g][j] = (short)(lo ? t1 : t3);
        }
    }

    float s1v[4][4], s2v[4][4];
    int i1v[4][4];
#pragma unroll
    for (int g = 0; g < 4; ++g)
#pragma unroll
        for (int r = 0; r < 4; ++r) { s1v[g][r] = FMAXV; s2v[g][r] = FMAXV; i1v[g][r] = 0; }

    int e = w;                 // eighth 0..7
    int nt0 = e * 64;
    const bf16x8* p1 = B1 + (size_t)nt0 * 64 + lane;
    const bf16x8* p2 = B2 + (size_t)nt0 * 64 + lane;
    const bf16x8* p3 = B3 + (size_t)nt0 * 64 + lane;
    const float* csqp = csq + nt0 * 16 + col;
    int idx = nt0 * 16 + col;

    for (int t = 0; t < 64; ++t) {
        bf16x8 b1 = p1[(size_t)t * 64];
        bf16x8 b2 = p2[(size_t)t * 64];
        bf16x8 b3 = p3[(size_t)t * 64];
        float cs = csqp[t * 16];
        f32x4 ini = {cs, cs, cs, cs};
#pragma unroll
        for (int g = 0; g < 4; ++g) {
            f32x4 acc = __builtin_amdgcn_mfma_f32_16x16x32_bf16(A1[g], b1, ini, 0, 0, 0);
            acc = __builtin_amdgcn_mfma_f32_16x16x32_bf16(A1[g], b2, acc, 0, 0, 0);
            acc = __builtin_amdgcn_mfma_f32_16x16x32_bf16(A2[g], b3, acc, 0, 0, 0);
#pragma unroll
            for (int r = 0; r < 4; ++r) {
                float s = acc[r];
                s2v[g][r] = fminf(s2v[g][r], fmaxf(s, s1v[g][r]));
                if (s < s1v[g][r]) i1v[g][r] = idx;
                s1v[g][r] = fminf(s1v[g][r], s);
            }
        }
        idx += 16;
    }

    // reduce across the 16 columns (lane bits 0-3)
#pragma unroll
    for (int m = 1; m < 16; m <<= 1) {
#pragma unroll
        for (int g = 0; g < 4; ++g)
#pragma unroll
            for (int r = 0; r < 4; ++r) {
                float os1 = __shfl_xor(s1v[g][r], m, 64);
                int   oi1 = __shfl_xor(i1v[g][r], m, 64);
                float os2 = __shfl_xor(s2v[g][r], m, 64);
                s2v[g][r] = fminf(fminf(s2v[g][r], os2), fmaxf(s1v[g][r], os1));
                bool take = (os1 < s1v[g][r]) || (os1 == s1v[g][r] && oi1 < i1v[g][r]);
                if (take) { s1v[g][r] = os1; i1v[g][r] = oi1; }
            }
    }
    if (col == 0) {
#pragma unroll
        for (int g = 0; g < 4; ++g)
#pragma unroll
            for (int r = 0; r < 4; ++r) {
                int rl = 16 * g + 4 * q + r;   // C/D row = quad*4 + reg
                m_s1[rl][e] = s1v[g][r];
                m_i1[rl][e] = i1v[g][r];
                m_s2[rl][e] = s2v[g][r];
            }
    }
    __syncthreads();
    if (tid < 64) {
        float best = FMAXV, s2 = FMAXV;
        int bi = 0;
#pragma unroll
        for (int ee = 0; ee < 8; ++ee) {   // ascending eighth = ascending code range
            float a1 = m_s1[tid][ee];
            int   ai = m_i1[tid][ee];
            float a2 = m_s2[tid][ee];
            s2 = fminf(fminf(s2, a2), fmaxf(best, a1));
            bool take = (a1 < best) || (a1 == best && ai < bi);
            if (take) { best = a1; bi = ai; }
        }
        int row = rowbase + tid;
        out[row] = bi;
        if (s2 - best < DELTA) {
            int pos = atomicAdd(counter, 1);
            queue[pos] = row;
        }
    }
}

// ---------------- K3: fallback — R1's fp32 arithmetic, bit-exact, queue-driven ----------------
__global__ __launch_bounds__(256) void fallback_kernel(const float* __restrict__ tprime,
                                                       const float* __restrict__ cb,
                                                       const float* __restrict__ csq,
                                                       const int* __restrict__ queue,
                                                       const int* __restrict__ counter,
                                                       int* __restrict__ out) {
    __shared__ unsigned long long red[4];
    int nq = counter[0];
    int tid = threadIdx.x;
    int lane = tid & 63;
    int w = tid >> 6;

    for (int qi = blockIdx.x; qi < nq; qi += 256) {
        int row = queue[qi];
        float tp[16];
        const float* tpp = tprime + (size_t)row * CD;
#pragma unroll
        for (int d = 0; d < 16; ++d) tp[d] = tpp[d];   // uniform -> broadcast

        float best = FMAXV;
        int bidx = 0;
#pragma unroll 2
        for (int i = 0; i < 32; ++i) {
            int k = tid + 256 * i;            // ascending per thread
            const float* cp = cb + (size_t)k * CD;
            float s = csq[k];
#pragma unroll
            for (int d = 0; d < 16; ++d) s += tp[d] * cp[d];
            if (s < best) { best = s; bidx = k; }
        }
        unsigned u = __float_as_uint(best);
        u = (u & 0x80000000u) ? ~u : (u | 0x80000000u);
        unsigned long long key = ((unsigned long long)u << 32) | (unsigned)bidx;
#pragma unroll
        for (int m = 1; m < 64; m <<= 1) {
            double od = __shfl_xor(__longlong_as_double((long long)key), m, 64);
            unsigned long long o = (unsigned long long)__double_as_longlong(od);
            key = o < key ? o : key;
        }
        if (lane == 0) red[w] = key;
        __syncthreads();
        if (tid == 0) {
            unsigned long long mm = red[0];
#pragma unroll
            for (int i = 1; i < 4; ++i) { unsigned long long x = red[i]; mm = x < mm ? x : mm; }
            out[row] = (int)(mm & 0xFFFFFFFFull);
        }
        __syncthreads();
    }
}

extern "C" void kernel_launch(void* const* d_in, const int* in_sizes, int n_in,
                              void* d_out, int out_size, void* d_ws, size_t ws_size,
                              hipStream_t stream) {
    const float* input = (const float*)d_in[0];  // (8,4096,512) fp32
    const float* W     = (const float*)d_in[1];  // (16,512) fp32
    const float* cb    = (const float*)d_in[2];  // (8192,16) fp32
    int* out = (int*)d_out;                      // (32768,) int32 labels

    float*  tprime  = (float*)d_ws;                       // 2 MB
    float*  csq     = tprime + (size_t)NROWS * CD;        // 32 KB
    bf16x8* B1      = (bf16x8*)(csq + CB);                // 512 KB each
    bf16x8* B2      = B1 + 32768;
    bf16x8* B3      = B2 + 32768;
    int*    counter = (int*)(B3 + 32768);
    int*    queue   = counter + 16;                       // 128 KB

    prep_kernel<<<32768 / 256, 256, 0, stream>>>(cb, csq, B1, B2, B3, counter);
    proj_kernel<<<NROWS / 16, 256, 0, stream>>>(input, W, tprime);
    scan_kernel<<<NROWS / 64, 512, 0, stream>>>(tprime, csq, B1, B2, B3, out, queue, counter);
    fallback_kernel<<<256, 256, 0, stream>>>(tprime, cb, csq, queue, counter, out);
}

// Round 8
// 210.218 us; speedup vs baseline: 1.1429x; 1.1429x over previous
//
#include <hip/hip_runtime.h>
#include <stdint.h>

#define IN_DIM 512
#define CB 8192
#define CD 16
#define NROWS 32768
#define DELTAQ 1.5e-2f
#define FMAXV 3.402823466e38f

typedef short bf16x8 __attribute__((ext_vector_type(8)));
typedef float f32x4 __attribute__((ext_vector_type(4)));

__device__ inline unsigned short f2bf(float x) {
    unsigned u = __float_as_uint(x);
    unsigned r = u + 0x7FFFu + ((u >> 16) & 1u);   // RNE
    return (unsigned short)(r >> 16);
}
__device__ inline float bf2f(unsigned short h) { return __uint_as_float(((unsigned)h) << 16); }
__device__ inline unsigned umin32(unsigned a, unsigned b) { return a < b ? a : b; }
__device__ inline unsigned umax32(unsigned a, unsigned b) { return a > b ? a : b; }
__device__ inline unsigned long long shfl_xor_u64(unsigned long long x, int m) {
    double d = __shfl_xor(__longlong_as_double((long long)x), m, 64);
    return (unsigned long long)__double_as_longlong(d);
}

// ---------------- K0: csq (R1-bit-exact) + csq+256 + 2-term B fragments ----------------
__global__ __launch_bounds__(256) void prep_kernel(const float* __restrict__ cb,
                                                   float* __restrict__ csq,
                                                   float* __restrict__ csqoff,
                                                   bf16x8* __restrict__ B1,
                                                   bf16x8* __restrict__ B2) {
    int id = blockIdx.x * 256 + threadIdx.x;  // 0..32767
    if (id < CB) {   // SOURCE-IDENTICAL csq expression (bit-exact vs R1)
        const float4* p = (const float4*)(cb + (size_t)id * CD);
        float s = 0.f;
#pragma unroll
        for (int j = 0; j < 4; ++j) {
            float4 v = p[j];
            s += v.x * v.x + v.y * v.y + v.z * v.z + v.w * v.w;
        }
        csq[id] = s;
        csqoff[id] = s + 256.0f;   // positive-score offset for packed epilogue (approx path only)
    }
    // 2-term bf16 split: B1=[c1|c1], B2=[c2|c2]; slot id = nt*64+lane
    int slot = id & 63;
    int nt = id >> 6;
    int q = slot >> 4;
    int n = nt * 16 + (slot & 15);
    int d0 = (q & 1) * 8;
    const float* src = cb + (size_t)n * CD + d0;
    bf16x8 v1, v2;
#pragma unroll
    for (int j = 0; j < 8; ++j) {
        float x = src[j];
        unsigned short a = f2bf(x);
        unsigned short b = f2bf(x - bf2f(a));
        v1[j] = (short)a;
        v2[j] = (short)b;
    }
    B1[id] = v1;
    B2[id] = v2;
}

// ---------------- K1: projection — R1's EXACT DAG, coalesced LDS staging ----------------
// Per (row,d): 4 chunk partials (serial j over 32 float4s, identical source
// expression), combined ((c0+c1)+c2)+c3, *(-2). Thread = (row=lane, dgroup=wave);
// input staged per-chunk into LDS with XOR swizzle (coalesced HBM, conflict-free
// LDS reads); W addresses wave-uniform -> s_load. Data movement only: bits preserved.
__global__ __launch_bounds__(256) void proj_kernel(const float* __restrict__ in,
                                                   const float* __restrict__ W,
                                                   float* __restrict__ tprime) {
    __shared__ float4 LIN[2048];   // 64 rows x 32 float4 (one 128-dim chunk), swizzled
    int tid = threadIdx.x;
    int lane = tid & 63;
    int dg = __builtin_amdgcn_readfirstlane(tid >> 6);   // d-group: d in [4dg, 4dg+4)
    int rowbase = blockIdx.x * 64;
    const float4* inp4 = (const float4*)in;

    float acc[4][4];   // [i][c]
#pragma unroll
    for (int i = 0; i < 4; ++i)
#pragma unroll
        for (int c = 0; c < 4; ++c) acc[i][c] = 0.f;

    for (int c = 0; c < 4; ++c) {
        __syncthreads();
#pragma unroll
        for (int u = 0; u < 8; ++u) {
            int f = tid + u * 256;         // 0..2047
            int r = f >> 5, o = f & 31;
            LIN[r * 32 + (o ^ (r & 7))] = inp4[(size_t)(rowbase + r) * 128 + c * 32 + o];
        }
        __syncthreads();
#pragma unroll 4
        for (int j = 0; j < 32; ++j) {
            float4 v = LIN[lane * 32 + (j ^ (lane & 7))];
#pragma unroll
            for (int i = 0; i < 4; ++i) {
                const float* w = W + (size_t)(4 * dg + i) * IN_DIM + c * 128 + j * 4;  // wave-uniform
                acc[i][c] += v.x * w[0] + v.y * w[1] + v.z * w[2] + v.w * w[3];
            }
        }
    }
    float4 o4;
    float t0 = -2.f * (((acc[0][0] + acc[0][1]) + acc[0][2]) + acc[0][3]);
    float t1 = -2.f * (((acc[1][0] + acc[1][1]) + acc[1][2]) + acc[1][3]);
    float t2 = -2.f * (((acc[2][0] + acc[2][1]) + acc[2][2]) + acc[2][3]);
    float t3 = -2.f * (((acc[3][0] + acc[3][1]) + acc[3][2]) + acc[3][3]);
    o4.x = t0; o4.y = t1; o4.z = t2; o4.w = t3;
    *(float4*)(tprime + (size_t)(rowbase + lane) * CD + 4 * dg) = o4;
}

// ---------------- K2: 2-MFMA scan + packed best-2 + inline exact fallback ----------------
// 512 blocks x 512 thr; 64 rows/block; wave e scans eighth e (64 tiles), G=4 rowgroups.
// Scores offset +256 (positive) -> float bits order as u32; key=(bits&~63)|tile.
__global__ __launch_bounds__(512, 4) void scan_kernel(
        const float* __restrict__ tprime, const float* __restrict__ csq,
        const float* __restrict__ csqoff,
        const bf16x8* __restrict__ B1, const bf16x8* __restrict__ B2,
        const float* __restrict__ cb, int* __restrict__ out) {
    __shared__ float tbuf[64][17];
    __shared__ unsigned long long m_k[64][8];
    __shared__ unsigned m_s2[64][8];
    __shared__ int flagged[64];
    __shared__ unsigned long long red[8];

    int tid = threadIdx.x;
    int lane = tid & 63;
    int e = __builtin_amdgcn_readfirstlane(tid >> 6);   // eighth 0..7
    int rowbase = blockIdx.x * 64;

    {   // stage t' tile (64 x 16), coalesced; tbuf also feeds the exact fallback
        int i0 = tid, i1 = tid + 512;
        tbuf[i0 >> 4][i0 & 15] = tprime[(size_t)rowbase * CD + i0];
        tbuf[i1 >> 4][i1 & 15] = tprime[(size_t)rowbase * CD + i1];
    }
    __syncthreads();

    int q = lane >> 4;
    int col = lane & 15;
    int d0 = (q & 1) * 8;
    bool lo = (q < 2);

    bf16x8 A1[4];   // per rowgroup: A[m=lane&15][k=q*8+j], [t1|t2]
#pragma unroll
    for (int g = 0; g < 4; ++g) {
        int arow = 16 * g + col;
#pragma unroll
        for (int j = 0; j < 8; ++j) {
            float x = tbuf[arow][d0 + j];
            unsigned short t1 = f2bf(x);
            unsigned short t2 = f2bf(x - bf2f(t1));
            A1[g][j] = (short)(lo ? t1 : t2);
        }
    }

    unsigned s1[4][4], s2[4][4];
#pragma unroll
    for (int g = 0; g < 4; ++g)
#pragma unroll
        for (int r = 0; r < 4; ++r) { s1[g][r] = 0xFFFFFFFFu; s2[g][r] = 0xFFFFFFFFu; }

    int nt0 = e * 64;
    const bf16x8* p1 = B1 + (size_t)nt0 * 64 + lane;
    const bf16x8* p2 = B2 + (size_t)nt0 * 64 + lane;
    const float* csqp = csqoff + nt0 * 16 + col;

#pragma unroll 4
    for (int t = 0; t < 64; ++t) {
        bf16x8 b1 = p1[(size_t)t * 64];
        bf16x8 b2 = p2[(size_t)t * 64];
        float cs = csqp[t * 16];
        f32x4 ini = {cs, cs, cs, cs};
        unsigned tt = (unsigned)t;
#pragma unroll
        for (int g = 0; g < 4; ++g) {
            f32x4 acc = __builtin_amdgcn_mfma_f32_16x16x32_bf16(A1[g], b1, ini, 0, 0, 0);
            acc = __builtin_amdgcn_mfma_f32_16x16x32_bf16(A1[g], b2, acc, 0, 0, 0);
#pragma unroll
            for (int r = 0; r < 4; ++r) {
                unsigned k = (__float_as_uint(acc[r]) & 0xFFFFFFC0u) | tt;
                s2[g][r] = umin32(s2[g][r], umax32(k, s1[g][r]));   // uses OLD s1
                s1[g][r] = umin32(s1[g][r], k);
            }
        }
    }

    // cross-col reduce (16 cols in lane bits 0-3); FK orders (qscore, e, tile, col) = (qscore, code)
#pragma unroll
    for (int g = 0; g < 4; ++g)
#pragma unroll
        for (int r = 0; r < 4; ++r) {
            unsigned long long FK = ((unsigned long long)(s1[g][r] & 0xFFFFFFC0u) << 13)
                                  | ((unsigned long long)e << 10)
                                  | ((unsigned long long)(s1[g][r] & 63u) << 4)
                                  | (unsigned long long)col;
            unsigned s2q = s2[g][r] & 0xFFFFFFC0u;
#pragma unroll
            for (int m = 1; m < 16; m <<= 1) {
                unsigned long long oFK = shfl_xor_u64(FK, m);
                unsigned os2 = (unsigned)__shfl_xor((int)s2q, m, 64);
                unsigned qa = (unsigned)(FK >> 13);
                unsigned qb = (unsigned)(oFK >> 13);
                s2q = umin32(umin32(s2q, os2), umax32(qa, qb));
                FK = oFK < FK ? oFK : FK;
            }
            if (col == 0) {
                int rl = 16 * g + 4 * q + r;   // C/D row = quad*4 + reg
                m_k[rl][e] = FK;
                m_s2[rl][e] = s2q;
            }
        }
    __syncthreads();

    if (tid < 64) {
        unsigned long long mFK = m_k[tid][0];
        unsigned g1 = (unsigned)(m_k[tid][0] >> 13);
        unsigned g2 = m_s2[tid][0];
#pragma unroll
        for (int ee = 1; ee < 8; ++ee) {
            unsigned long long F = m_k[tid][ee];
            unsigned u = (unsigned)(F >> 13);
            if (u < g1) { g2 = g1; g1 = u; } else { g2 = umin32(g2, u); }
            g2 = umin32(g2, m_s2[tid][ee]);
            mFK = F < mFK ? F : mFK;
        }
        int ccol = (int)(mFK & 15ull);
        int ctile = (int)((mFK >> 4) & 63ull);
        int ce = (int)((mFK >> 10) & 7ull);
        out[rowbase + tid] = ((ce * 64 + ctile) << 4) | ccol;
        flagged[tid] = (__uint_as_float(g2) - __uint_as_float(g1) < DELTAQ) ? 1 : 0;
    }
    __syncthreads();

    // ---- inline exact fallback: R1's fp32 serial-FMA chain, whole block per row ----
    for (int fi = 0; fi < 64; ++fi) {
        if (!flagged[fi]) continue;
        int row = rowbase + fi;
        float tp[16];
#pragma unroll
        for (int d = 0; d < 16; ++d) tp[d] = tbuf[fi][d];   // uniform -> broadcast
        float best = FMAXV;
        int bidx = 0;
#pragma unroll 2
        for (int ii = 0; ii < 16; ++ii) {
            int k = tid + 512 * ii;            // ascending per thread, coalesced
            const float* cp = cb + (size_t)k * CD;
            float s = csq[k];
#pragma unroll
            for (int d = 0; d < 16; ++d) s += tp[d] * cp[d];
            if (s < best) { best = s; bidx = k; }
        }
        unsigned u = __float_as_uint(best);
        u = (u & 0x80000000u) ? ~u : (u | 0x80000000u);
        unsigned long long key = ((unsigned long long)u << 32) | (unsigned)bidx;
#pragma unroll
        for (int m = 1; m < 64; m <<= 1) {
            unsigned long long o = shfl_xor_u64(key, m);
            key = o < key ? o : key;
        }
        if (lane == 0) red[e] = key;
        __syncthreads();
        if (tid == 0) {
            unsigned long long mm = red[0];
#pragma unroll
            for (int i = 1; i < 8; ++i) { unsigned long long x = red[i]; mm = x < mm ? x : mm; }
            out[row] = (int)(mm & 0xFFFFFFFFull);
        }
        __syncthreads();
    }
}

extern "C" void kernel_launch(void* const* d_in, const int* in_sizes, int n_in,
                              void* d_out, int out_size, void* d_ws, size_t ws_size,
                              hipStream_t stream) {
    const float* input = (const float*)d_in[0];  // (8,4096,512) fp32
    const float* W     = (const float*)d_in[1];  // (16,512) fp32
    const float* cb    = (const float*)d_in[2];  // (8192,16) fp32
    int* out = (int*)d_out;                      // (32768,) int32 labels

    float*  tprime = (float*)d_ws;                        // 2 MB
    float*  csq    = tprime + (size_t)NROWS * CD;         // 32 KB
    float*  csqoff = csq + CB;                            // 32 KB
    bf16x8* B1     = (bf16x8*)(csqoff + CB);              // 512 KB each
    bf16x8* B2     = B1 + 32768;

    prep_kernel<<<32768 / 256, 256, 0, stream>>>(cb, csq, csqoff, B1, B2);
    proj_kernel<<<NROWS / 64, 256, 0, stream>>>(input, W, tprime);
    scan_kernel<<<NROWS / 64, 512, 0, stream>>>(tprime, csq, csqoff, B1, B2, cb, out);
}

// Round 9
// 192.874 us; speedup vs baseline: 1.2456x; 1.0899x over previous
//
#include <hip/hip_runtime.h>
#include <stdint.h>

#define IN_DIM 512
#define CB 8192
#define CD 16
#define NROWS 32768
#define DELTAQ 1.5e-2f
#define FMAXV 3.402823466e38f

typedef short bf16x8 __attribute__((ext_vector_type(8)));
typedef float f32x4 __attribute__((ext_vector_type(4)));

__device__ inline unsigned short f2bf(float x) {
    unsigned u = __float_as_uint(x);
    unsigned r = u + 0x7FFFu + ((u >> 16) & 1u);   // RNE
    return (unsigned short)(r >> 16);
}
__device__ inline float bf2f(unsigned short h) { return __uint_as_float(((unsigned)h) << 16); }
__device__ inline unsigned umin32(unsigned a, unsigned b) { return a < b ? a : b; }
__device__ inline unsigned umax32(unsigned a, unsigned b) { return a > b ? a : b; }
__device__ inline unsigned long long shfl_xor_u64(unsigned long long x, int m) {
    double d = __shfl_xor(__longlong_as_double((long long)x), m, 64);
    return (unsigned long long)__double_as_longlong(d);
}

// ---------------- K0: csq (R1-bit-exact) + csq+256 + packed B fragments ----------------
// Bp = [c1 | c2] in the two K-halves of one 16x16x32 B-fragment.
__global__ __launch_bounds__(256) void prep_kernel(const float* __restrict__ cb,
                                                   float* __restrict__ csq,
                                                   float* __restrict__ csqoff,
                                                   bf16x8* __restrict__ Bp) {
    int id = blockIdx.x * 256 + threadIdx.x;  // 0..32767
    if (id < CB) {   // SOURCE-IDENTICAL csq expression (bit-exact vs R1)
        const float4* p = (const float4*)(cb + (size_t)id * CD);
        float s = 0.f;
#pragma unroll
        for (int j = 0; j < 4; ++j) {
            float4 v = p[j];
            s += v.x * v.x + v.y * v.y + v.z * v.z + v.w * v.w;
        }
        csq[id] = s;
        csqoff[id] = s + 256.0f;   // positive-score offset for packed keys (approx path only)
    }
    // slot id = nt*64 + lane; B[k][n]: n = lane&15, k = (lane>>4)*8 + j
    int slot = id & 63;
    int nt = id >> 6;
    int q = slot >> 4;
    int n = nt * 16 + (slot & 15);
    int d0 = (q & 1) * 8;
    bool lo = (q < 2);          // k<16 -> c1[d], k>=16 -> c2[d]
    const float* src = cb + (size_t)n * CD + d0;
    bf16x8 v;
#pragma unroll
    for (int j = 0; j < 8; ++j) {
        float x = src[j];
        unsigned short a = f2bf(x);
        unsigned short b = f2bf(x - bf2f(a));
        v[j] = (short)(lo ? a : b);
    }
    Bp[id] = v;
}

// ---------------- K1a: projection partials — sacred DAG, one chunk per block ----------------
// Block (strip, c): 64 rows x chunk c (128 dims). Per (row, d): serial j-fold over
// 32 float4s with the identical source expression. 2048 blocks -> 4x occupancy of R8.
__global__ __launch_bounds__(256) void proj_partial_kernel(const float* __restrict__ in,
                                                           const float* __restrict__ W,
                                                           float* __restrict__ partials) {
    __shared__ float4 LIN[2048];   // 64 rows x 32 float4, swizzled
    int tid = threadIdx.x;
    int lane = tid & 63;
    int dg = __builtin_amdgcn_readfirstlane(tid >> 6);   // d-group: d in [4dg, 4dg+4)
    int strip = blockIdx.x >> 2;
    int c = blockIdx.x & 3;
    int rowbase = strip * 64;
    const float4* inp4 = (const float4*)in;

#pragma unroll
    for (int u = 0; u < 8; ++u) {
        int f = tid + u * 256;         // 0..2047
        int r = f >> 5, o = f & 31;
        LIN[r * 32 + (o ^ (r & 7))] = inp4[(size_t)(rowbase + r) * 128 + c * 32 + o];
    }
    __syncthreads();

    float acc[4];
#pragma unroll
    for (int i = 0; i < 4; ++i) acc[i] = 0.f;
#pragma unroll 4
    for (int j = 0; j < 32; ++j) {
        float4 v = LIN[lane * 32 + (j ^ (lane & 7))];
#pragma unroll
        for (int i = 0; i < 4; ++i) {
            const float* w = W + (size_t)(4 * dg + i) * IN_DIM + c * 128 + j * 4;  // wave-uniform
            acc[i] += v.x * w[0] + v.y * w[1] + v.z * w[2] + v.w * w[3];
        }
    }
    float* o = partials + (size_t)c * NROWS * CD + (size_t)(rowbase + lane) * CD + 4 * dg;
#pragma unroll
    for (int i = 0; i < 4; ++i) o[i] = acc[i];
}

// ---------------- K1b: combine — ((c0+c1)+c2)+c3 fold, *(-2) (bit-exact lineage) ----------------
__global__ __launch_bounds__(256) void proj_combine_kernel(const float* __restrict__ partials,
                                                           float* __restrict__ tprime) {
    int idx = blockIdx.x * 256 + threadIdx.x;   // 0 .. 524287
    const size_t P = (size_t)NROWS * CD;
    float p0 = partials[idx];
    float p1 = partials[P + idx];
    float p2 = partials[2 * P + idx];
    float p3 = partials[3 * P + idx];
    tprime[idx] = -2.f * (((p0 + p1) + p2) + p3);
}

// ---------------- K2: packed-B scan (1 load, 2 MFMA / tile / rowgroup) + fallback ----------------
// 1024 blocks x 512 thr; 32 rows/block (G=2 rowgroups); wave e scans eighth e (64 tiles).
__global__ __launch_bounds__(512, 8) void scan_kernel(
        const float* __restrict__ tprime, const float* __restrict__ csq,
        const float* __restrict__ csqoff, const bf16x8* __restrict__ Bp,
        const float* __restrict__ cb, int* __restrict__ out) {
    __shared__ float tbuf[32][17];
    __shared__ unsigned long long m_k[32][8];
    __shared__ unsigned m_s2[32][8];
    __shared__ int flagged[32];
    __shared__ unsigned long long red[8];

    int tid = threadIdx.x;
    int lane = tid & 63;
    int e = __builtin_amdgcn_readfirstlane(tid >> 6);   // eighth 0..7
    int rowbase = blockIdx.x * 32;

    if (tid < 512) {   // stage t' tile (32 x 16) coalesced
        tbuf[tid >> 4][tid & 15] = tprime[(size_t)rowbase * CD + tid];
    }
    __syncthreads();

    int q = lane >> 4;
    int col = lane & 15;
    int d0 = (q & 1) * 8;
    bool lo = (q < 2);

    bf16x8 A1[2], A2[2];   // per rowgroup: A1=[t1|t1], A2=[t2|0]
#pragma unroll
    for (int g = 0; g < 2; ++g) {
        int arow = 16 * g + col;
#pragma unroll
        for (int j = 0; j < 8; ++j) {
            float x = tbuf[arow][d0 + j];
            unsigned short t1 = f2bf(x);
            unsigned short t2 = f2bf(x - bf2f(t1));
            A1[g][j] = (short)t1;
            A2[g][j] = (short)(lo ? t2 : 0);
        }
    }

    unsigned s1[2][4], s2[2][4];
#pragma unroll
    for (int g = 0; g < 2; ++g)
#pragma unroll
        for (int r = 0; r < 4; ++r) { s1[g][r] = 0xFFFFFFFFu; s2[g][r] = 0xFFFFFFFFu; }

    int nt0 = e * 64;
    const bf16x8* pb = Bp + (size_t)nt0 * 64 + lane;
    const float* csqp = csqoff + nt0 * 16 + col;

#pragma unroll 4
    for (int t = 0; t < 64; ++t) {
        bf16x8 b = pb[(size_t)t * 64];
        float cs = csqp[t * 16];
        f32x4 ini = {cs, cs, cs, cs};
        unsigned tt = (unsigned)t;
#pragma unroll
        for (int g = 0; g < 2; ++g) {
            f32x4 acc = __builtin_amdgcn_mfma_f32_16x16x32_bf16(A1[g], b, ini, 0, 0, 0);
            acc = __builtin_amdgcn_mfma_f32_16x16x32_bf16(A2[g], b, acc, 0, 0, 0);
#pragma unroll
            for (int r = 0; r < 4; ++r) {
                unsigned k = (__float_as_uint(acc[r]) & 0xFFFFFFC0u) | tt;
                s2[g][r] = umin32(s2[g][r], umax32(k, s1[g][r]));   // uses OLD s1
                s1[g][r] = umin32(s1[g][r], k);
            }
        }
    }

    // cross-col reduce; FK orders (qscore, e, tile, col) = (qscore, code)
#pragma unroll
    for (int g = 0; g < 2; ++g)
#pragma unroll
        for (int r = 0; r < 4; ++r) {
            unsigned long long FK = ((unsigned long long)(s1[g][r] & 0xFFFFFFC0u) << 13)
                                  | ((unsigned long long)e << 10)
                                  | ((unsigned long long)(s1[g][r] & 63u) << 4)
                                  | (unsigned long long)col;
            unsigned s2q = s2[g][r] & 0xFFFFFFC0u;
#pragma unroll
            for (int m = 1; m < 16; m <<= 1) {
                unsigned long long oFK = shfl_xor_u64(FK, m);
                unsigned os2 = (unsigned)__shfl_xor((int)s2q, m, 64);
                unsigned qa = (unsigned)(FK >> 13);
                unsigned qb = (unsigned)(oFK >> 13);
                s2q = umin32(umin32(s2q, os2), umax32(qa, qb));
                FK = oFK < FK ? oFK : FK;
            }
            if (col == 0) {
                int rl = 16 * g + 4 * q + r;   // C/D row = quad*4 + reg
                m_k[rl][e] = FK;
                m_s2[rl][e] = s2q;
            }
        }
    __syncthreads();

    if (tid < 32) {
        unsigned long long mFK = m_k[tid][0];
        unsigned g1 = (unsigned)(m_k[tid][0] >> 13);
        unsigned g2 = m_s2[tid][0];
#pragma unroll
        for (int ee = 1; ee < 8; ++ee) {
            unsigned long long F = m_k[tid][ee];
            unsigned u = (unsigned)(F >> 13);
            if (u < g1) { g2 = g1; g1 = u; } else { g2 = umin32(g2, u); }
            g2 = umin32(g2, m_s2[tid][ee]);
            mFK = F < mFK ? F : mFK;
        }
        int ccol = (int)(mFK & 15ull);
        int ctile = (int)((mFK >> 4) & 63ull);
        int ce = (int)((mFK >> 10) & 7ull);
        out[rowbase + tid] = ((ce * 64 + ctile) << 4) | ccol;
        flagged[tid] = (__uint_as_float(g2) - __uint_as_float(g1) < DELTAQ) ? 1 : 0;
    }
    __syncthreads();

    // ---- inline exact fallback: R1's fp32 serial-FMA chain (bit-exact, verified) ----
    for (int fi = 0; fi < 32; ++fi) {
        if (!flagged[fi]) continue;
        int row = rowbase + fi;
        float tp[16];
#pragma unroll
        for (int d = 0; d < 16; ++d) tp[d] = tbuf[fi][d];   // uniform -> broadcast
        float best = FMAXV;
        int bidx = 0;
#pragma unroll 2
        for (int ii = 0; ii < 16; ++ii) {
            int k = tid + 512 * ii;            // ascending per thread, coalesced
            const float* cp = cb + (size_t)k * CD;
            float s = csq[k];
#pragma unroll
            for (int d = 0; d < 16; ++d) s += tp[d] * cp[d];
            if (s < best) { best = s; bidx = k; }
        }
        unsigned u = __float_as_uint(best);
        u = (u & 0x80000000u) ? ~u : (u | 0x80000000u);
        unsigned long long key = ((unsigned long long)u << 32) | (unsigned)bidx;
#pragma unroll
        for (int m = 1; m < 64; m <<= 1) {
            unsigned long long o = shfl_xor_u64(key, m);
            key = o < key ? o : key;
        }
        if (lane == 0) red[e] = key;
        __syncthreads();
        if (tid == 0) {
            unsigned long long mm = red[0];
#pragma unroll
            for (int i = 1; i < 8; ++i) { unsigned long long x = red[i]; mm = x < mm ? x : mm; }
            out[row] = (int)(mm & 0xFFFFFFFFull);
        }
        __syncthreads();
    }
}

extern "C" void kernel_launch(void* const* d_in, const int* in_sizes, int n_in,
                              void* d_out, int out_size, void* d_ws, size_t ws_size,
                              hipStream_t stream) {
    const float* input = (const float*)d_in[0];  // (8,4096,512) fp32
    const float* W     = (const float*)d_in[1];  // (16,512) fp32
    const float* cb    = (const float*)d_in[2];  // (8192,16) fp32
    int* out = (int*)d_out;                      // (32768,) int32 labels

    float*  tprime   = (float*)d_ws;                      // 2 MB
    float*  csq      = tprime + (size_t)NROWS * CD;       // 32 KB
    float*  csqoff   = csq + CB;                          // 32 KB
    bf16x8* Bp       = (bf16x8*)(csqoff + CB);            // 512 KB
    float*  partials = (float*)(Bp + 32768);              // 8 MB (4 x 2 MB)

    prep_kernel<<<32768 / 256, 256, 0, stream>>>(cb, csq, csqoff, Bp);
    proj_partial_kernel<<<(NROWS / 64) * 4, 256, 0, stream>>>(input, W, partials);
    proj_combine_kernel<<<NROWS * CD / 256, 256, 0, stream>>>(partials, tprime);
    scan_kernel<<<NROWS / 32, 512, 0, stream>>>(tprime, csq, csqoff, Bp, cb, out);
}

// Round 10
// 169.656 us; speedup vs baseline: 1.4161x; 1.1369x over previous
//
#include <hip/hip_runtime.h>
#include <stdint.h>

#define IN_DIM 512
#define CB 8192
#define CD 16
#define NROWS 32768
#define DELTAQ 8e-3f
#define FMAXV 3.402823466e38f

typedef short bf16x8 __attribute__((ext_vector_type(8)));
typedef float f32x4 __attribute__((ext_vector_type(4)));

__device__ inline unsigned short f2bf(float x) {
    unsigned u = __float_as_uint(x);
    unsigned r = u + 0x7FFFu + ((u >> 16) & 1u);   // RNE
    return (unsigned short)(r >> 16);
}
__device__ inline float bf2f(unsigned short h) { return __uint_as_float(((unsigned)h) << 16); }
__device__ inline unsigned umin32(unsigned a, unsigned b) { return a < b ? a : b; }
__device__ inline unsigned umax32(unsigned a, unsigned b) { return a > b ? a : b; }
__device__ inline unsigned long long shfl_xor_u64(unsigned long long x, int m) {
    double d = __shfl_xor(__longlong_as_double((long long)x), m, 64);
    return (unsigned long long)__double_as_longlong(d);
}

// ---------------- K0: csq (R1-bit-exact) + csq+256 + packed B fragments + counter ----------------
// Bp = [c1 | c2] in the two K-halves of one 16x16x32 B-fragment.
__global__ __launch_bounds__(256) void prep_kernel(const float* __restrict__ cb,
                                                   float* __restrict__ csq,
                                                   float* __restrict__ csqoff,
                                                   bf16x8* __restrict__ Bp,
                                                   int* __restrict__ counter) {
    int id = blockIdx.x * 256 + threadIdx.x;  // 0..32767
    if (id == 0) counter[0] = 0;
    if (id < CB) {   // SOURCE-IDENTICAL csq expression (bit-exact vs R1)
        const float4* p = (const float4*)(cb + (size_t)id * CD);
        float s = 0.f;
#pragma unroll
        for (int j = 0; j < 4; ++j) {
            float4 v = p[j];
            s += v.x * v.x + v.y * v.y + v.z * v.z + v.w * v.w;
        }
        csq[id] = s;
        csqoff[id] = s + 256.0f;   // positive-score offset for packed keys (approx path only)
    }
    int slot = id & 63;
    int nt = id >> 6;
    int q = slot >> 4;
    int n = nt * 16 + (slot & 15);
    int d0 = (q & 1) * 8;
    bool lo = (q < 2);          // k<16 -> c1[d], k>=16 -> c2[d]
    const float* src = cb + (size_t)n * CD + d0;
    bf16x8 v;
#pragma unroll
    for (int j = 0; j < 8; ++j) {
        float x = src[j];
        unsigned short a = f2bf(x);
        unsigned short b = f2bf(x - bf2f(a));
        v[j] = (short)(lo ? a : b);
    }
    Bp[id] = v;
}

// ---------------- K1a: projection partials — sacred DAG, pure-LDS inner loop ----------------
// Block (strip, c): 64 rows x chunk c (128 dims). W chunk-slice (16x128, 8 KB) and the
// input chunk both staged in LDS; inner loop has ZERO global/scalar loads (no lgkm mixing).
// Input LDS layout transposed+XOR-swizzled: write [o][r^(o&7)], read [j][lane^(j&7)]
// -> both phases canonical conflict-free. Arithmetic: serial j-fold per chunk (R1 DAG).
__global__ __launch_bounds__(256) void proj_partial_kernel(const float* __restrict__ in,
                                                           const float* __restrict__ W,
                                                           float* __restrict__ partials) {
    __shared__ float4 LIN[2048];        // [o=0..31][r=0..63] swizzled
    __shared__ float4 WL[16 * 33];      // [d][j] with pad: row stride 33 f4
    int tid = threadIdx.x;
    int lane = tid & 63;
    int dg = __builtin_amdgcn_readfirstlane(tid >> 6);   // d-group: d in [4dg, 4dg+4)
    int strip = blockIdx.x >> 2;
    int c = blockIdx.x & 3;
    int rowbase = strip * 64;
    const float4* inp4 = (const float4*)in;
    const float4* W4 = (const float4*)W;

    // stage W slice: d rows 0..15, chunk c: 16 x 32 f4
#pragma unroll
    for (int u = 0; u < 2; ++u) {
        int f = tid + u * 256;          // 0..511
        int d = f >> 5, o = f & 31;
        WL[d * 33 + o] = W4[(size_t)d * 128 + c * 32 + o];
    }
    // stage input chunk: 64 rows x 32 f4, transposed-swizzled
#pragma unroll
    for (int u = 0; u < 8; ++u) {
        int f = tid + u * 256;          // 0..2047
        int o = f & 31, r = f >> 5;     // consecutive tid -> consecutive o: global coalesced
        LIN[o * 64 + (r ^ (o & 7))] = inp4[(size_t)(rowbase + r) * 128 + c * 32 + o];
    }
    __syncthreads();

    float acc[4];
#pragma unroll
    for (int i = 0; i < 4; ++i) acc[i] = 0.f;
#pragma unroll 4
    for (int j = 0; j < 32; ++j) {
        float4 v = LIN[j * 64 + (lane ^ (j & 7))];
#pragma unroll
        for (int i = 0; i < 4; ++i) {
            float4 w = WL[(4 * dg + i) * 33 + j];   // wave-uniform -> LDS broadcast
            acc[i] += v.x * w.x + v.y * w.y + v.z * w.z + v.w * w.w;
        }
    }
    float* o = partials + (size_t)c * NROWS * CD + (size_t)(rowbase + lane) * CD + 4 * dg;
#pragma unroll
    for (int i = 0; i < 4; ++i) o[i] = acc[i];
}

// ---------------- K1b: combine — ((c0+c1)+c2)+c3 fold, *(-2) (bit-exact lineage) ----------------
__global__ __launch_bounds__(256) void proj_combine_kernel(const float* __restrict__ partials,
                                                           float* __restrict__ tprime) {
    int idx = blockIdx.x * 256 + threadIdx.x;   // 0 .. 524287
    const size_t P = (size_t)NROWS * CD;
    float p0 = partials[idx];
    float p1 = partials[P + idx];
    float p2 = partials[2 * P + idx];
    float p3 = partials[3 * P + idx];
    tprime[idx] = -2.f * (((p0 + p1) + p2) + p3);
}

// ---------------- K2: packed-B scan (1 load, 2 MFMA / tile / rowgroup), queue flags ----------------
// 1024 blocks x 512 thr; 32 rows/block (G=2); wave e scans eighth e (64 tiles).
__global__ __launch_bounds__(512, 6) void scan_kernel(
        const float* __restrict__ tprime, const float* __restrict__ csqoff,
        const bf16x8* __restrict__ Bp, int* __restrict__ out,
        int* __restrict__ queue, int* __restrict__ counter) {
    __shared__ float tbuf[32][17];
    __shared__ unsigned long long m_k[32][8];
    __shared__ unsigned m_s2[32][8];

    int tid = threadIdx.x;
    int lane = tid & 63;
    int e = __builtin_amdgcn_readfirstlane(tid >> 6);   // eighth 0..7
    int rowbase = blockIdx.x * 32;

    tbuf[tid >> 4][tid & 15] = tprime[(size_t)rowbase * CD + tid];
    __syncthreads();

    int q = lane >> 4;
    int col = lane & 15;
    int d0 = (q & 1) * 8;
    bool lo = (q < 2);

    bf16x8 A1[2], A2[2];   // per rowgroup: A1=[t1|t1], A2=[t2|0]
#pragma unroll
    for (int g = 0; g < 2; ++g) {
        int arow = 16 * g + col;
#pragma unroll
        for (int j = 0; j < 8; ++j) {
            float x = tbuf[arow][d0 + j];
            unsigned short t1 = f2bf(x);
            unsigned short t2 = f2bf(x - bf2f(t1));
            A1[g][j] = (short)t1;
            A2[g][j] = (short)(lo ? t2 : 0);
        }
    }

    unsigned s1[2][4], s2[2][4];
#pragma unroll
    for (int g = 0; g < 2; ++g)
#pragma unroll
        for (int r = 0; r < 4; ++r) { s1[g][r] = 0xFFFFFFFFu; s2[g][r] = 0xFFFFFFFFu; }

    int nt0 = e * 64;
    const bf16x8* pb = Bp + (size_t)nt0 * 64 + lane;
    const float* csqp = csqoff + nt0 * 16 + col;

#pragma unroll 4
    for (int t = 0; t < 64; ++t) {
        bf16x8 b = pb[(size_t)t * 64];
        float cs = csqp[t * 16];
        f32x4 ini = {cs, cs, cs, cs};
        unsigned tt = (unsigned)t;
#pragma unroll
        for (int g = 0; g < 2; ++g) {
            f32x4 acc = __builtin_amdgcn_mfma_f32_16x16x32_bf16(A1[g], b, ini, 0, 0, 0);
            acc = __builtin_amdgcn_mfma_f32_16x16x32_bf16(A2[g], b, acc, 0, 0, 0);
#pragma unroll
            for (int r = 0; r < 4; ++r) {
                unsigned k = (__float_as_uint(acc[r]) & 0xFFFFFFC0u) | tt;
                s2[g][r] = umin32(s2[g][r], umax32(k, s1[g][r]));   // uses OLD s1
                s1[g][r] = umin32(s1[g][r], k);
            }
        }
    }

    // cross-col reduce; FK orders (qscore, e, tile, col) = (qscore, code)
#pragma unroll
    for (int g = 0; g < 2; ++g)
#pragma unroll
        for (int r = 0; r < 4; ++r) {
            unsigned long long FK = ((unsigned long long)(s1[g][r] & 0xFFFFFFC0u) << 13)
                                  | ((unsigned long long)e << 10)
                                  | ((unsigned long long)(s1[g][r] & 63u) << 4)
                                  | (unsigned long long)col;
            unsigned s2q = s2[g][r] & 0xFFFFFFC0u;
#pragma unroll
            for (int m = 1; m < 16; m <<= 1) {
                unsigned long long oFK = shfl_xor_u64(FK, m);
                unsigned os2 = (unsigned)__shfl_xor((int)s2q, m, 64);
                unsigned qa = (unsigned)(FK >> 13);
                unsigned qb = (unsigned)(oFK >> 13);
                s2q = umin32(umin32(s2q, os2), umax32(qa, qb));
                FK = oFK < FK ? oFK : FK;
            }
            if (col == 0) {
                int rl = 16 * g + 4 * q + r;   // C/D row = quad*4 + reg
                m_k[rl][e] = FK;
                m_s2[rl][e] = s2q;
            }
        }
    __syncthreads();

    if (tid < 32) {
        unsigned long long mFK = m_k[tid][0];
        unsigned g1 = (unsigned)(m_k[tid][0] >> 13);
        unsigned g2 = m_s2[tid][0];
#pragma unroll
        for (int ee = 1; ee < 8; ++ee) {
            unsigned long long F = m_k[tid][ee];
            unsigned u = (unsigned)(F >> 13);
            if (u < g1) { g2 = g1; g1 = u; } else { g2 = umin32(g2, u); }
            g2 = umin32(g2, m_s2[tid][ee]);
            mFK = F < mFK ? F : mFK;
        }
        int ccol = (int)(mFK & 15ull);
        int ctile = (int)((mFK >> 4) & 63ull);
        int ce = (int)((mFK >> 10) & 7ull);
        int row = rowbase + tid;
        out[row] = ((ce * 64 + ctile) << 4) | ccol;
        if (__uint_as_float(g2) - __uint_as_float(g1) < DELTAQ) {
            int pos = atomicAdd(counter, 1);
            queue[pos] = row;
        }
    }
}

// ---------------- K3: fallback — R1's fp32 arithmetic, bit-exact, queue-driven ----------------
__global__ __launch_bounds__(256) void fallback_kernel(const float* __restrict__ tprime,
                                                       const float* __restrict__ cb,
                                                       const float* __restrict__ csq,
                                                       const int* __restrict__ queue,
                                                       const int* __restrict__ counter,
                                                       int* __restrict__ out) {
    __shared__ unsigned long long red[4];
    int nq = counter[0];
    int tid = threadIdx.x;
    int lane = tid & 63;
    int w = tid >> 6;

    for (int qi = blockIdx.x; qi < nq; qi += 256) {
        int row = queue[qi];
        float tp[16];
        const float* tpp = tprime + (size_t)row * CD;
#pragma unroll
        for (int d = 0; d < 16; ++d) tp[d] = tpp[d];   // uniform -> broadcast

        float best = FMAXV;
        int bidx = 0;
#pragma unroll 2
        for (int i = 0; i < 32; ++i) {
            int k = tid + 256 * i;            // ascending per thread
            const float* cp = cb + (size_t)k * CD;
            float s = csq[k];
#pragma unroll
            for (int d = 0; d < 16; ++d) s += tp[d] * cp[d];
            if (s < best) { best = s; bidx = k; }
        }
        unsigned u = __float_as_uint(best);
        u = (u & 0x80000000u) ? ~u : (u | 0x80000000u);
        unsigned long long key = ((unsigned long long)u << 32) | (unsigned)bidx;
#pragma unroll
        for (int m = 1; m < 64; m <<= 1) {
            unsigned long long o = shfl_xor_u64(key, m);
            key = o < key ? o : key;
        }
        if (lane == 0) red[w] = key;
        __syncthreads();
        if (tid == 0) {
            unsigned long long mm = red[0];
#pragma unroll
            for (int i = 1; i < 4; ++i) { unsigned long long x = red[i]; mm = x < mm ? x : mm; }
            out[row] = (int)(mm & 0xFFFFFFFFull);
        }
        __syncthreads();
    }
}

extern "C" void kernel_launch(void* const* d_in, const int* in_sizes, int n_in,
                              void* d_out, int out_size, void* d_ws, size_t ws_size,
                              hipStream_t stream) {
    const float* input = (const float*)d_in[0];  // (8,4096,512) fp32
    const float* W     = (const float*)d_in[1];  // (16,512) fp32
    const float* cb    = (const float*)d_in[2];  // (8192,16) fp32
    int* out = (int*)d_out;                      // (32768,) int32 labels

    float*  tprime   = (float*)d_ws;                      // 2 MB
    float*  csq      = tprime + (size_t)NROWS * CD;       // 32 KB
    float*  csqoff   = csq + CB;                          // 32 KB
    bf16x8* Bp       = (bf16x8*)(csqoff + CB);            // 512 KB
    float*  partials = (float*)(Bp + 32768);              // 8 MB
    int*    counter  = (int*)(partials + 4 * (size_t)NROWS * CD);
    int*    queue    = counter + 16;                      // 128 KB

    prep_kernel<<<32768 / 256, 256, 0, stream>>>(cb, csq, csqoff, Bp, counter);
    proj_partial_kernel<<<(NROWS / 64) * 4, 256, 0, stream>>>(input, W, partials);
    proj_combine_kernel<<<NROWS * CD / 256, 256, 0, stream>>>(partials, tprime);
    scan_kernel<<<NROWS / 32, 512, 0, stream>>>(tprime, csqoff, Bp, out, queue, counter);
    fallback_kernel<<<256, 256, 0, stream>>>(tprime, cb, csq, queue, counter, out);
}